// Round 1
// baseline (82319.281 us; speedup 1.0000x reference)
//
#include <hip/hip_runtime.h>
#include <math.h>

// KalmanNet forward: T=2048 sequential steps, persistent cooperative kernel.
// 250 blocks x 512 threads (1 block/CU, 8 waves). 2 grid barriers per step.
//
// Per step:
//   head   (wave0, redundant/block): prior=f@post, m1y=h@prior, innov, l2norms, x_in,
//          then all threads: a1=relu(W1@x_in+b1) with W1 in registers.
//   PhaseA (distributed): wave w of block b owns hidden unit u=8b+w; 3 dots over a1[1600]
//          + 3 dots over hn[2000] (float4, streamed from L3), GRU gates -> hn_new[u].
//   bar1 -> PhaseB (distributed): stage hn_new->LDS; blocks<200 each: 2 rows of W2@hn_new,
//          fold W3 with innov (k_gain never materialized) -> 10 atomicAdd partials.
//   bar2 -> next head finalizes post_new redundantly; block0 writes output.

#define T_STEPS 2048
#define H1      1600
#define HID     2000
#define NBLK    250
#define NTHR    512
#define DPAD    64      // delta accumulator padding (floats) to spread atomics
#define RMAGIC  0x1357u

struct Params {
  const float *y, *f, *h, *m1x0, *hn0, *W1, *b1, *Wih, *Whh, *bih, *bhh, *W2, *b2, *W3, *b3;
  float* out;
  float* w3t;     // [400*100] transposed W3
  float* hn_g;    // [2*2000] double-buffered hidden state
  float* delta;   // [2*10*DPAD] atomic partial sums of k_gain@innov
  unsigned* bar;  // [0]=cnt, [32]=gen, [64]=ready
};

__device__ __forceinline__ float dot4(float4 w, float4 x, float acc) {
  acc = fmaf(w.x, x.x, acc); acc = fmaf(w.y, x.y, acc);
  acc = fmaf(w.z, x.z, acc); acc = fmaf(w.w, x.w, acc);
  return acc;
}

__device__ __forceinline__ float wave_reduce(float v) {
#pragma unroll
  for (int o = 32; o > 0; o >>= 1) v += __shfl_xor(v, o, 64);
  return v;
}

__device__ __forceinline__ float sigm(float x) { return 1.0f / (1.0f + expf(-x)); }

__device__ __forceinline__ void gbar(unsigned* cnt, unsigned* gen) {
  __syncthreads();
  if (threadIdx.x == 0) {
    __threadfence();
    unsigned g = __hip_atomic_load(gen, __ATOMIC_RELAXED, __HIP_MEMORY_SCOPE_AGENT);
    unsigned prev = __hip_atomic_fetch_add(cnt, 1u, __ATOMIC_RELAXED, __HIP_MEMORY_SCOPE_AGENT);
    if (prev == NBLK - 1) {
      __hip_atomic_store(cnt, 0u, __ATOMIC_RELAXED, __HIP_MEMORY_SCOPE_AGENT);
      __threadfence();
      __hip_atomic_store(gen, g + 1u, __ATOMIC_RELAXED, __HIP_MEMORY_SCOPE_AGENT);
    } else {
      while (__hip_atomic_load(gen, __ATOMIC_RELAXED, __HIP_MEMORY_SCOPE_AGENT) == g)
        __builtin_amdgcn_s_sleep(1);
    }
    __threadfence();
  }
  __syncthreads();
}

__global__ __launch_bounds__(NTHR, 2) void knet_kernel(Params p) {
  const int tid  = threadIdx.x;
  const int blk  = blockIdx.x;
  const int wv   = tid >> 6;
  const int lane = tid & 63;

  __shared__ __align__(16) float a1_lds[H1];
  __shared__ __align__(16) float hn_lds[HID];
  __shared__ float f_lds[100], h_lds[100], b3_lds[100];
  __shared__ float xin_lds[20];
  __shared__ float post_lds[10], prpv_lds[10], prior_lds[10], innov_lds[10];
  __shared__ float pd_lds[2][10];

  // ---------------- setup ----------------
  if (tid < 100) { f_lds[tid] = p.f[tid]; h_lds[tid] = p.h[tid]; b3_lds[tid] = p.b3[tid]; }
  if (tid < 10)  { post_lds[tid] = p.m1x0[tid]; prpv_lds[tid] = p.m1x0[tid]; }
  for (int i = tid; i < HID / 4; i += NTHR)
    ((float4*)hn_lds)[i] = ((const float4*)p.hn0)[i];

  // W1 (1600x20) + b1 into registers: thread holds rows tid, tid+512, tid+1024, (+1536 if tid<64)
  float w1reg[4][20]; float b1reg[4];
#pragma unroll
  for (int k = 0; k < 4; ++k) {
    int r = tid + NTHR * k;
    b1reg[k] = 0.f;
#pragma unroll
    for (int c = 0; c < 20; ++c) w1reg[k][c] = 0.f;
    if (r < H1) {
      b1reg[k] = p.b1[r];
#pragma unroll
      for (int c = 0; c < 20; ++c) w1reg[k][c] = p.W1[r * 20 + c];
    }
  }

  // per-wave GRU unit + biases
  const int u = blk * 8 + wv;                    // 0..1999, exact cover
  const float bihr = p.bih[u], bihz = p.bih[HID + u], bihn = p.bih[2 * HID + u];
  const float bhhr = p.bhh[u], bhhz = p.bhh[HID + u], bhhn = p.bhh[2 * HID + u];

  // PhaseB row assignment (blocks 0..199, waves 0..1 -> rows 0..399)
  const int s_row = blk * 2 + wv;
  float b2reg = 0.f;
  if (blk < 200 && wv < 2) b2reg = p.b2[s_row];

  // transpose W3 (100x400 -> 400x100) into workspace
  if (blk < 200 && tid < 100) {
    int s0 = blk * 2, s1 = blk * 2 + 1;
    p.w3t[s0 * 100 + tid] = p.W3[tid * 400 + s0];
    p.w3t[s1 * 100 + tid] = p.W3[tid * 400 + s1];
  }

  // barrier/delta init (ws is poisoned 0xAA before every launch)
  if (blk == 0) {
    for (int i = tid; i < 2 * 10 * DPAD; i += NTHR) p.delta[i] = 0.f;
    __syncthreads();
    if (tid == 0) {
      __hip_atomic_store(p.bar + 0,  0u, __ATOMIC_RELAXED, __HIP_MEMORY_SCOPE_AGENT);
      __hip_atomic_store(p.bar + 32, 0u, __ATOMIC_RELAXED, __HIP_MEMORY_SCOPE_AGENT);
      __threadfence();
      __hip_atomic_store(p.bar + 64, RMAGIC, __ATOMIC_RELAXED, __HIP_MEMORY_SCOPE_AGENT);
    }
  } else {
    if (tid == 0) {
      while (__hip_atomic_load(p.bar + 64, __ATOMIC_RELAXED, __HIP_MEMORY_SCOPE_AGENT) != RMAGIC)
        __builtin_amdgcn_s_sleep(1);
      __threadfence();
    }
  }
  __syncthreads();

  // ---------------- main loop ----------------
  for (int t = 0; t <= T_STEPS; ++t) {
    if (wv == 0) {
      const bool act = lane < 10;
      if (t > 0) {
        // finalize step t-1: post_new = prior + delta + (b3-fold with innov(t-1))
        float pr_old = act ? prior_lds[lane] : 0.f;
        float dsum   = act ? p.delta[((t - 1) & 1) * 10 * DPAD + lane * DPAD] : 0.f;
        float b3f = 0.f;
        if (act) {
#pragma unroll
          for (int c = 0; c < 10; ++c) b3f = fmaf(innov_lds[c], b3_lds[lane * 10 + c], b3f);
        }
        float postn = pr_old + dsum + b3f;
        if (act) {
          prpv_lds[lane] = pr_old;
          post_lds[lane] = postn;
          if (blk == 0) p.out[lane * T_STEPS + (t - 1)] = postn;
        }
      }
      if (t < T_STEPS) {
        float pr = 0.f;
        if (act) {
#pragma unroll
          for (int j = 0; j < 10; ++j) pr = fmaf(f_lds[lane * 10 + j], post_lds[j], pr);
          prior_lds[lane] = pr;
        }
        float m1y = 0.f;
#pragma unroll
        for (int j = 0; j < 10; ++j) {
          float prj = __shfl(pr, j, 64);
          if (act) m1y = fmaf(h_lds[lane * 10 + j], prj, m1y);
        }
        float yv  = act ? p.y[lane * T_STEPS + t] : 0.f;
        float inn = act ? (yv - m1y) : 0.f;
        float s1 = inn * inn;
#pragma unroll
        for (int o = 8; o > 0; o >>= 1) s1 += __shfl_xor(s1, o, 16);
        float dm1y = inn / fmaxf(sqrtf(s1), 1e-12f);
        float dx = act ? (post_lds[lane] - prpv_lds[lane]) : 0.f;
        float s2 = dx * dx;
#pragma unroll
        for (int o = 8; o > 0; o >>= 1) s2 += __shfl_xor(s2, o, 16);
        float dm1x = dx / fmaxf(sqrtf(s2), 1e-12f);
        if (act) {
          xin_lds[lane]      = dm1y;
          xin_lds[10 + lane] = dm1x;
          innov_lds[lane]    = inn;
        }
      }
    }
    if (t == T_STEPS) break;
    __syncthreads();

    // a1 = relu(W1 @ x_in + b1), W1 in registers
#pragma unroll
    for (int k = 0; k < 4; ++k) {
      int r = tid + NTHR * k;
      if (r < H1) {
        float acc = b1reg[k];
#pragma unroll
        for (int c = 0; c < 20; ++c) acc = fmaf(w1reg[k][c], xin_lds[c], acc);
        a1_lds[r] = fmaxf(acc, 0.f);
      }
    }
    __syncthreads();

    // PhaseA: gi = W_ih@a1, gh = W_hh@hn, gates, hn_new[u]
    {
      const float4* a1v = (const float4*)a1_lds;
      const float4* hnv = (const float4*)hn_lds;
      const float4* wr = (const float4*)(p.Wih + (size_t)u * H1);
      const float4* wz = (const float4*)(p.Wih + (size_t)(HID + u) * H1);
      const float4* wn = (const float4*)(p.Wih + (size_t)(2 * HID + u) * H1);
      float gr = 0.f, gz = 0.f, gn = 0.f;
#pragma unroll
      for (int j = 0; j < 7; ++j) {
        int fi = lane + 64 * j;
        if (fi < H1 / 4) {
          float4 x = a1v[fi];
          gr = dot4(wr[fi], x, gr);
          gz = dot4(wz[fi], x, gz);
          gn = dot4(wn[fi], x, gn);
        }
      }
      const float4* vr = (const float4*)(p.Whh + (size_t)u * HID);
      const float4* vz = (const float4*)(p.Whh + (size_t)(HID + u) * HID);
      const float4* vn = (const float4*)(p.Whh + (size_t)(2 * HID + u) * HID);
      float hr = 0.f, hz = 0.f, hg = 0.f;
#pragma unroll
      for (int j = 0; j < 8; ++j) {
        int fi = lane + 64 * j;
        if (fi < HID / 4) {
          float4 x = hnv[fi];
          hr = dot4(vr[fi], x, hr);
          hz = dot4(vz[fi], x, hz);
          hg = dot4(vn[fi], x, hg);
        }
      }
      gr = wave_reduce(gr); gz = wave_reduce(gz); gn = wave_reduce(gn);
      hr = wave_reduce(hr); hz = wave_reduce(hz); hg = wave_reduce(hg);
      float rg = sigm(gr + bihr + hr + bhhr);
      float zg = sigm(gz + bihz + hz + bhhz);
      float ng = tanhf(gn + bihn + rg * (hg + bhhn));
      float hnew = (1.f - zg) * ng + zg * hn_lds[u];
      if (lane == 0) p.hn_g[(t & 1) * HID + u] = hnew;
    }
    gbar(p.bar + 0, p.bar + 32);

    // PhaseB: stage hn_new; a2 rows; fold W3 with innov -> 10 atomic partials
    {
      const int par = t & 1;
      for (int i = tid; i < HID / 4; i += NTHR)
        ((float4*)hn_lds)[i] = ((const float4*)(p.hn_g + par * HID))[i];
      __syncthreads();
      if (blk < 200 && wv < 2) {
        const float4* w2v = (const float4*)(p.W2 + (size_t)s_row * HID);
        const float4* hnv = (const float4*)hn_lds;
        float acc = 0.f;
#pragma unroll
        for (int j = 0; j < 8; ++j) {
          int fi = lane + 64 * j;
          if (fi < HID / 4) acc = dot4(w2v[fi], hnv[fi], acc);
        }
        acc = wave_reduce(acc);
        float a2s = fmaxf(acc + b2reg, 0.f);
        if (lane < 10) {
          float mr = 0.f;
#pragma unroll
          for (int c = 0; c < 10; ++c)
            mr = fmaf(innov_lds[c], p.w3t[s_row * 100 + lane * 10 + c], mr);
          pd_lds[wv][lane] = a2s * mr;
        }
      }
      __syncthreads();
      if (blk < 200 && tid < 10)
        atomicAdd(&p.delta[par * 10 * DPAD + tid * DPAD], pd_lds[0][tid] + pd_lds[1][tid]);
      if (blk == 0)
        for (int i = tid; i < 10 * DPAD; i += NTHR) p.delta[(par ^ 1) * 10 * DPAD + i] = 0.f;
    }
    gbar(p.bar + 0, p.bar + 32);
  }
}

extern "C" void kernel_launch(void* const* d_in, const int* in_sizes, int n_in,
                              void* d_out, int out_size, void* d_ws, size_t ws_size,
                              hipStream_t stream) {
  Params p;
  p.y    = (const float*)d_in[0];
  p.f    = (const float*)d_in[1];
  p.h    = (const float*)d_in[2];
  p.m1x0 = (const float*)d_in[3];
  p.hn0  = (const float*)d_in[4];
  p.W1   = (const float*)d_in[5];
  p.b1   = (const float*)d_in[6];
  p.Wih  = (const float*)d_in[7];
  p.Whh  = (const float*)d_in[8];
  p.bih  = (const float*)d_in[9];
  p.bhh  = (const float*)d_in[10];
  p.W2   = (const float*)d_in[11];
  p.b2   = (const float*)d_in[12];
  p.W3   = (const float*)d_in[13];
  p.b3   = (const float*)d_in[14];
  p.out  = (float*)d_out;

  float* ws = (float*)d_ws;
  p.w3t   = ws;                       // 40000 floats
  p.hn_g  = ws + 40000;               // 4000 floats (16B aligned: 40000*4 % 16 == 0)
  p.delta = ws + 44000;               // 1280 floats
  p.bar   = (unsigned*)(ws + 45312);  // 3 slots, 128B apart

  void* args[] = { &p };
  hipLaunchCooperativeKernel((const void*)knet_kernel, dim3(NBLK), dim3(NTHR),
                             args, 0, stream);
}

// Round 2
// 53946.716 us; speedup vs baseline: 1.5259x; 1.5259x over previous
//
#include <hip/hip_runtime.h>
#include <math.h>

// KalmanNet forward, persistent cooperative kernel, T=2048 serial steps.
// Round 2: GRU weights (Wih 38.4MB + Whh 48MB) pinned in VGPRs (one hidden
// unit per wave, ~188 regs/lane); W2 register-pinned (2 rows/block, split
// over 4 waves); W1 streamed from L2 (read-only, L2-resident). Per step
// global traffic ~2MB (hn exchange) instead of 90MB weight streaming.
//
// 250 blocks x 512 threads, 8 waves/block, 1 block/CU, 2 grid barriers/step.

#define T_STEPS 2048
#define H1      1600
#define HID     2000
#define NBLK    250
#define NTHR    512
#define DPAD    64
#define RMAGIC  0x1357u

struct Params {
  const float *y, *f, *h, *m1x0, *hn0, *W1, *b1, *Wih, *Whh, *bih, *bhh, *W2, *b2, *W3, *b3;
  float* out;
  float* w3t;     // [400*100] transposed W3
  float* hn_g;    // [2*2000] double-buffered hidden state
  float* delta;   // [2*10*DPAD]
  unsigned* bar;  // [0]=cnt, [32]=gen, [64]=ready
};

__device__ __forceinline__ float dot4(float4 w, float4 x, float acc) {
  acc = fmaf(w.x, x.x, acc); acc = fmaf(w.y, x.y, acc);
  acc = fmaf(w.z, x.z, acc); acc = fmaf(w.w, x.w, acc);
  return acc;
}

__device__ __forceinline__ float wave_reduce(float v) {
#pragma unroll
  for (int o = 32; o > 0; o >>= 1) v += __shfl_xor(v, o, 64);
  return v;
}

__device__ __forceinline__ float sigm(float x) { return 1.0f / (1.0f + expf(-x)); }

__device__ __forceinline__ void gbar(unsigned* cnt, unsigned* gen) {
  __syncthreads();
  if (threadIdx.x == 0) {
    __threadfence();
    unsigned g = __hip_atomic_load(gen, __ATOMIC_RELAXED, __HIP_MEMORY_SCOPE_AGENT);
    unsigned prev = __hip_atomic_fetch_add(cnt, 1u, __ATOMIC_RELAXED, __HIP_MEMORY_SCOPE_AGENT);
    if (prev == NBLK - 1) {
      __hip_atomic_store(cnt, 0u, __ATOMIC_RELAXED, __HIP_MEMORY_SCOPE_AGENT);
      __threadfence();
      __hip_atomic_store(gen, g + 1u, __ATOMIC_RELAXED, __HIP_MEMORY_SCOPE_AGENT);
    } else {
      while (__hip_atomic_load(gen, __ATOMIC_RELAXED, __HIP_MEMORY_SCOPE_AGENT) == g)
        __builtin_amdgcn_s_sleep(1);
    }
    __threadfence();
  }
  __syncthreads();
}

__global__ __launch_bounds__(NTHR, 2) void knet_kernel(Params p) {
  const int tid  = threadIdx.x;
  const int blk  = blockIdx.x;
  const int wv   = tid >> 6;
  const int lane = tid & 63;

  // LDS: a1 padded to 448 float4, hn padded to 512 float4 (pads zeroed once)
  __shared__ __align__(16) float a1_lds[1792];
  __shared__ __align__(16) float hn_lds[2048];
  __shared__ float f_lds[100], h_lds[100], b3_lds[100];
  __shared__ float xin_lds[20];
  __shared__ float post_lds[10], prpv_lds[10], prior_lds[10], innov_lds[10];
  __shared__ float a2part_lds[8];
  __shared__ float a2_lds[2], b2_lds[2];

  // ---------------- setup ----------------
  if (tid < 100) { f_lds[tid] = p.f[tid]; h_lds[tid] = p.h[tid]; b3_lds[tid] = p.b3[tid]; }
  if (tid < 10)  { post_lds[tid] = p.m1x0[tid]; prpv_lds[tid] = p.m1x0[tid]; }
  if (tid < 500) ((float4*)hn_lds)[tid] = ((const float4*)p.hn0)[tid];
  if (tid < 48)  hn_lds[2000 + tid] = 0.f;
  if (tid < 192) a1_lds[1600 + tid] = 0.f;

  // per-wave GRU unit: weights into registers
  const int u = blk * 8 + wv;                    // 0..1999, exact cover
  float4 wih[3][7];                              // fi4 = lane + 64*j, valid < 400
  float4 whh[3][8];                              // fi4 = lane + 64*j, valid < 500
  const float4 z4 = make_float4(0.f, 0.f, 0.f, 0.f);
#pragma unroll
  for (int g = 0; g < 3; ++g) {
    const float4* rw = (const float4*)(p.Wih + (size_t)(g * HID + u) * H1);
#pragma unroll
    for (int j = 0; j < 7; ++j) {
      int fi = lane + 64 * j;
      wih[g][j] = (fi < 400) ? rw[fi] : z4;
    }
    const float4* rv = (const float4*)(p.Whh + (size_t)(g * HID + u) * HID);
#pragma unroll
    for (int j = 0; j < 8; ++j) {
      int fi = lane + 64 * j;
      whh[g][j] = (fi < 500) ? rv[fi] : z4;
    }
  }
  const float bihr = p.bih[u], bihz = p.bih[HID + u], bihn = p.bih[2 * HID + u];
  const float bhhr = p.bhh[u], bhhz = p.bhh[HID + u], bhhn = p.bhh[2 * HID + u];

  // W2: blocks 0..199 hold rows 2b (waves 0-3) and 2b+1 (waves 4-7),
  // each wave holds a 500-float chunk c = wv&3 of its row.
  const int w2row = blk * 2 + (wv >> 2);
  const int w2c   = wv & 3;
  float4 w2r[2];
  w2r[0] = z4; w2r[1] = z4;
  if (blk < 200) {
    const float4* rw2 = (const float4*)(p.W2 + (size_t)w2row * HID);
#pragma unroll
    for (int k = 0; k < 2; ++k) {
      int fi = w2c * 125 + lane + 64 * k;
      if (lane + 64 * k < 125) w2r[k] = rw2[fi];
    }
    if (tid < 2) b2_lds[tid] = p.b2[blk * 2 + tid];
    if (tid < 100) {
      int s0 = blk * 2, s1 = blk * 2 + 1;
      p.w3t[s0 * 100 + tid] = p.W3[tid * 400 + s0];
      p.w3t[s1 * 100 + tid] = p.W3[tid * 400 + s1];
    }
  }

  // barrier/delta init (ws poisoned 0xAA before every launch)
  if (blk == 0) {
    for (int i = tid; i < 2 * 10 * DPAD; i += NTHR) p.delta[i] = 0.f;
    __syncthreads();
    if (tid == 0) {
      __hip_atomic_store(p.bar + 0,  0u, __ATOMIC_RELAXED, __HIP_MEMORY_SCOPE_AGENT);
      __hip_atomic_store(p.bar + 32, 0u, __ATOMIC_RELAXED, __HIP_MEMORY_SCOPE_AGENT);
      __threadfence();
      __hip_atomic_store(p.bar + 64, RMAGIC, __ATOMIC_RELAXED, __HIP_MEMORY_SCOPE_AGENT);
    }
  } else {
    if (tid == 0) {
      while (__hip_atomic_load(p.bar + 64, __ATOMIC_RELAXED, __HIP_MEMORY_SCOPE_AGENT) != RMAGIC)
        __builtin_amdgcn_s_sleep(1);
      __threadfence();
    }
  }
  __syncthreads();

  // ---------------- main loop ----------------
  for (int t = 0; t <= T_STEPS; ++t) {
    if (wv == 0) {
      const bool act = lane < 10;
      if (t > 0) {
        float pr_old = act ? prior_lds[lane] : 0.f;
        float dsum   = act ? p.delta[((t - 1) & 1) * 10 * DPAD + lane * DPAD] : 0.f;
        float b3f = 0.f;
        if (act) {
#pragma unroll
          for (int c = 0; c < 10; ++c) b3f = fmaf(innov_lds[c], b3_lds[lane * 10 + c], b3f);
        }
        float postn = pr_old + dsum + b3f;
        if (act) {
          prpv_lds[lane] = pr_old;
          post_lds[lane] = postn;
          if (blk == 0) p.out[lane * T_STEPS + (t - 1)] = postn;
        }
      }
      if (t < T_STEPS) {
        float pr = 0.f;
        if (act) {
#pragma unroll
          for (int j = 0; j < 10; ++j) pr = fmaf(f_lds[lane * 10 + j], post_lds[j], pr);
          prior_lds[lane] = pr;
        }
        float m1y = 0.f;
#pragma unroll
        for (int j = 0; j < 10; ++j) {
          float prj = __shfl(pr, j, 64);
          if (act) m1y = fmaf(h_lds[lane * 10 + j], prj, m1y);
        }
        float yv  = act ? p.y[lane * T_STEPS + t] : 0.f;
        float inn = act ? (yv - m1y) : 0.f;
        float s1 = inn * inn;
#pragma unroll
        for (int o = 8; o > 0; o >>= 1) s1 += __shfl_xor(s1, o, 16);
        float dm1y = inn / fmaxf(sqrtf(s1), 1e-12f);
        float dx = act ? (post_lds[lane] - prpv_lds[lane]) : 0.f;
        float s2 = dx * dx;
#pragma unroll
        for (int o = 8; o > 0; o >>= 1) s2 += __shfl_xor(s2, o, 16);
        float dm1x = dx / fmaxf(sqrtf(s2), 1e-12f);
        if (act) {
          xin_lds[lane]      = dm1y;
          xin_lds[10 + lane] = dm1x;
          innov_lds[lane]    = inn;
        }
      }
    }
    if (t == T_STEPS) break;
    __syncthreads();

    // a1 = relu(W1 @ x_in + b1); W1 streamed from L2 (read-only resident)
#pragma unroll
    for (int k = 0; k < 4; ++k) {
      int r = tid + NTHR * k;
      if (r < H1) {
        const float4* w1r = (const float4*)(p.W1 + (size_t)r * 20);
        float acc = p.b1[r];
#pragma unroll
        for (int q = 0; q < 5; ++q) {
          float4 w = w1r[q];
          acc = fmaf(w.x, xin_lds[q * 4 + 0], acc);
          acc = fmaf(w.y, xin_lds[q * 4 + 1], acc);
          acc = fmaf(w.z, xin_lds[q * 4 + 2], acc);
          acc = fmaf(w.w, xin_lds[q * 4 + 3], acc);
        }
        a1_lds[r] = fmaxf(acc, 0.f);
      }
    }
    __syncthreads();

    // PhaseA: gates from register weights, LDS activations
    {
      const float4* a1v = (const float4*)a1_lds;
      const float4* hnv = (const float4*)hn_lds;
      float gr = 0.f, gz = 0.f, gn = 0.f;
#pragma unroll
      for (int j = 0; j < 7; ++j) {
        float4 x = a1v[lane + 64 * j];          // pads zeroed, weights zeroed
        gr = dot4(wih[0][j], x, gr);
        gz = dot4(wih[1][j], x, gz);
        gn = dot4(wih[2][j], x, gn);
      }
      float hr = 0.f, hz = 0.f, hg = 0.f;
#pragma unroll
      for (int j = 0; j < 8; ++j) {
        float4 x = hnv[lane + 64 * j];
        hr = dot4(whh[0][j], x, hr);
        hz = dot4(whh[1][j], x, hz);
        hg = dot4(whh[2][j], x, hg);
      }
      gr = wave_reduce(gr); gz = wave_reduce(gz); gn = wave_reduce(gn);
      hr = wave_reduce(hr); hz = wave_reduce(hz); hg = wave_reduce(hg);
      float rg = sigm(gr + bihr + hr + bhhr);
      float zg = sigm(gz + bihz + hz + bhhz);
      float ng = tanhf(gn + bihn + rg * (hg + bhhn));
      float hnew = (1.f - zg) * ng + zg * hn_lds[u];
      if (lane == 0) p.hn_g[(t & 1) * HID + u] = hnew;
    }
    gbar(p.bar + 0, p.bar + 32);

    // PhaseB: stage hn_new; distributed W2 rows; W3-fold -> 10 atomics
    {
      const int par = t & 1;
      if (tid < 500)
        ((float4*)hn_lds)[tid] = ((const float4*)(p.hn_g + par * HID))[tid];
      __syncthreads();
      if (blk < 200) {
        const float4* hnv = (const float4*)hn_lds;
        float acc = 0.f;
#pragma unroll
        for (int k = 0; k < 2; ++k)
          acc = dot4(w2r[k], hnv[w2c * 125 + lane + 64 * k], acc);
        acc = wave_reduce(acc);
        if (lane == 0) a2part_lds[wv] = acc;
      }
      __syncthreads();
      if (blk < 200) {
        if (tid < 2)
          a2_lds[tid] = fmaxf(a2part_lds[tid * 4] + a2part_lds[tid * 4 + 1] +
                              a2part_lds[tid * 4 + 2] + a2part_lds[tid * 4 + 3] +
                              b2_lds[tid], 0.f);
      }
      __syncthreads();
      if (blk < 200 && wv == 0 && lane < 20) {
        int q = lane / 10, col = lane % 10;
        int row = blk * 2 + q;
        float mr = 0.f;
#pragma unroll
        for (int c = 0; c < 10; ++c)
          mr = fmaf(innov_lds[c], p.w3t[row * 100 + col * 10 + c], mr);
        float v = a2_lds[q] * mr;
        float v2 = __shfl(v, lane + 10, 64);
        if (lane < 10)
          atomicAdd(&p.delta[par * 10 * DPAD + lane * DPAD], v + v2);
      }
      if (blk == 0)
        for (int i = tid; i < 10 * DPAD; i += NTHR) p.delta[(par ^ 1) * 10 * DPAD + i] = 0.f;
    }
    gbar(p.bar + 0, p.bar + 32);
  }
}

extern "C" void kernel_launch(void* const* d_in, const int* in_sizes, int n_in,
                              void* d_out, int out_size, void* d_ws, size_t ws_size,
                              hipStream_t stream) {
  Params p;
  p.y    = (const float*)d_in[0];
  p.f    = (const float*)d_in[1];
  p.h    = (const float*)d_in[2];
  p.m1x0 = (const float*)d_in[3];
  p.hn0  = (const float*)d_in[4];
  p.W1   = (const float*)d_in[5];
  p.b1   = (const float*)d_in[6];
  p.Wih  = (const float*)d_in[7];
  p.Whh  = (const float*)d_in[8];
  p.bih  = (const float*)d_in[9];
  p.bhh  = (const float*)d_in[10];
  p.W2   = (const float*)d_in[11];
  p.b2   = (const float*)d_in[12];
  p.W3   = (const float*)d_in[13];
  p.b3   = (const float*)d_in[14];
  p.out  = (float*)d_out;

  float* ws = (float*)d_ws;
  p.w3t   = ws;                       // 40000 floats
  p.hn_g  = ws + 40000;               // 4000 floats
  p.delta = ws + 44000;               // 1280 floats
  p.bar   = (unsigned*)(ws + 45312);  // 3 slots, 128B apart

  void* args[] = { &p };
  hipLaunchCooperativeKernel((const void*)knet_kernel, dim3(NBLK), dim3(NTHR),
                             args, 0, stream);
}